// Round 5
// baseline (30.433 us; speedup 1.0000x reference)
//
#include <hip/hip_runtime.h>

// OversizeConv2d via MFMA: Z = A_h * X * A_w^T + hb*s_w[ow] + wb per (b,c) image.
// Pass A: P = X * Aw^T (X staged coalesced into LDS, bf16).
// Pass B (operand-swapped): Z^T = PT * Ah^T -> j-contiguous float4 nontemporal stores.
// Block = one channel, 4 images; grid 1024 (4 blocks/CU, zero tail).
// Prefetch distance = 1 full iteration; barriers are LDS-only (no vmcnt drain).

#define STRB 72   // bf16 LDS row stride: 144 B

typedef short  bfrag  __attribute__((ext_vector_type(8)));   // 8 bf16 = 4 VGPR
typedef float  f32x4  __attribute__((ext_vector_type(4)));
typedef unsigned short us4 __attribute__((ext_vector_type(4)));

__device__ __forceinline__ unsigned short f2bf(float f) {
    unsigned u = __builtin_bit_cast(unsigned, f);
    u += 0x7fffu + ((u >> 16) & 1u);          // round-to-nearest-even
    return (unsigned short)(u >> 16);
}

// LDS-visibility barrier WITHOUT vmcnt drain (keeps global loads/stores in flight)
__device__ __forceinline__ void lds_barrier() {
    asm volatile("s_waitcnt lgkmcnt(0)" ::: "memory");
    __builtin_amdgcn_s_barrier();
}

__global__ __launch_bounds__(256, 4)
void oversize_conv_v5(const float* __restrict__ x,
                      const float* __restrict__ hwt,   // (128,1,13,1)
                      const float* __restrict__ wwt,   // (128,1,1,13)
                      const float* __restrict__ hb,
                      const float* __restrict__ wb,
                      float* __restrict__ out)
{
    __shared__ __align__(16) unsigned short Xs[64 * STRB];  // X bf16 [h][w]
    __shared__ __align__(16) unsigned short Aw[64 * STRB];  // Aw[ow][iw] (B^T, pass A)
    __shared__ __align__(16) unsigned short Ah[64 * STRB];  // Ah[oh][ih] (B^T, pass B swapped)
    __shared__ __align__(16) unsigned short PT[64 * STRB];  // P^T [ow][h]
    __shared__ float hk[128], wk[128], swp[256];
    __shared__ __align__(16) float sw[64];

    const int tid = threadIdx.x;
    const int c   = blockIdx.x & 127;          // channel
    const int g4  = blockIdx.x >> 7;           // batch group: batches 4*g4 .. 4*g4+3
    const size_t imgStride = (size_t)128 * 4096;
    const size_t img0 = ((size_t)(4 * g4) * 128 + c) * 4096;

    const int wv = tid >> 6, lane = tid & 63;
    const int r = lane & 15, gq = lane >> 4;

    // ---- image 0 -> regs, fully coalesced (issue before setup math)
    float4 xv[4];
    {
        const float4* xg = (const float4*)(x + img0);
        #pragma unroll
        for (int q = 0; q < 4; ++q) xv[q] = xg[tid + q * 256];
    }

    // ---- interpolate 13 -> 127 taps (align_corners linear)
    if (tid < 127) {
        const float scale = 12.0f / 126.0f;
        float pos = (float)tid * scale;
        int   lo  = (int)pos;
        float fr  = pos - (float)lo;
        int   hi  = (lo + 1 < 12) ? lo + 1 : 12;
        hk[tid] = hwt[c * 13 + lo] * (1.0f - fr) + hwt[c * 13 + hi] * fr;
        wk[tid] = wwt[c * 13 + lo] * (1.0f - fr) + wwt[c * 13 + hi] * fr;
    }
    lds_barrier();

    // ---- build Toeplitz factors (bf16), once per block
    {
        const int row = tid >> 2;            // 0..63
        const int cb  = (tid & 3) * 16;
        #pragma unroll
        for (int q = 0; q < 4; ++q) {
            us4 vh, vw;
            #pragma unroll
            for (int j = 0; j < 4; ++j) {
                int col = cb + q * 4 + j;
                vh[j] = f2bf(hk[col - row + 63]);
                vw[j] = f2bf(wk[col - row + 63]);
            }
            *(us4*)&Ah[row * STRB + cb + q * 4] = vh;
            *(us4*)&Aw[row * STRB + cb + q * 4] = vw;
        }
    }
    // ---- s_w partials: 4 threads per ow, 16 taps each
    {
        const int ow = tid >> 2, q = tid & 3;
        float s = 0.f;
        #pragma unroll
        for (int i = 0; i < 16; ++i) s += wk[(q * 16 + i) - ow + 63];
        swp[tid] = s;
    }
    // ---- stage image 0 into Xs (coalesced layout -> LDS)
    #pragma unroll
    for (int q = 0; q < 4; ++q) {
        int idx = tid + q * 256;
        int row = idx >> 4;
        int col = (idx & 15) * 4;
        us4 v;
        v[0] = f2bf(xv[q].x); v[1] = f2bf(xv[q].y);
        v[2] = f2bf(xv[q].z); v[3] = f2bf(xv[q].w);
        *(us4*)&Xs[row * STRB + col] = v;
    }
    // ---- prefetch image 1 (consumed at bottom of iter 0 -> ~full-iter cover)
    float4 xn[4];
    {
        const float4* xg = (const float4*)(x + img0 + imgStride);
        #pragma unroll
        for (int q = 0; q < 4; ++q) xn[q] = xg[tid + q * 256];
    }
    lds_barrier();

    if (tid < 64)
        sw[tid] = swp[4 * tid] + swp[4 * tid + 1] + swp[4 * tid + 2] + swp[4 * tid + 3];
    // sw becomes visible to all waves at iter-0's mid barrier, before first use.

    const float hbc = hb[c], wbc = wb[c];

    #pragma unroll
    for (int i = 0; i < 4; ++i) {
        // ---- pass A: P = X * Aw^T (wave wv owns P rows 16wv..16wv+15)
        bfrag a0 = *(const bfrag*)&Xs[(16 * wv + r) * STRB + 8 * gq];
        bfrag a1 = *(const bfrag*)&Xs[(16 * wv + r) * STRB + 32 + 8 * gq];
        f32x4 acc[4] = {};
        #pragma unroll
        for (int nt = 0; nt < 4; ++nt) {
            bfrag b0 = *(const bfrag*)&Aw[(16 * nt + r) * STRB + 8 * gq];
            bfrag b1 = *(const bfrag*)&Aw[(16 * nt + r) * STRB + 32 + 8 * gq];
            acc[nt] = __builtin_amdgcn_mfma_f32_16x16x32_bf16(a0, b0, acc[nt], 0, 0, 0);
            acc[nt] = __builtin_amdgcn_mfma_f32_16x16x32_bf16(a1, b1, acc[nt], 0, 0, 0);
        }
        // ---- write P transposed: PT[ow=16nt+r][h=16wv+4gq+j]
        #pragma unroll
        for (int nt = 0; nt < 4; ++nt) {
            us4 p;
            p[0] = f2bf(acc[nt][0]); p[1] = f2bf(acc[nt][1]);
            p[2] = f2bf(acc[nt][2]); p[3] = f2bf(acc[nt][3]);
            *(us4*)&PT[(16 * nt + r) * STRB + 16 * wv + 4 * gq] = p;
        }
        lds_barrier();   // PT (and sw on first pass) visible; all Xs reads done

        // ---- pass B (swapped): Z^T = PT * Ah^T
        f32x4 sw4 = *(const f32x4*)&sw[16 * wv + 4 * gq];
        f32x4 bias;
        bias[0] = hbc * sw4[0] + wbc; bias[1] = hbc * sw4[1] + wbc;
        bias[2] = hbc * sw4[2] + wbc; bias[3] = hbc * sw4[3] + wbc;

        bfrag pa0 = *(const bfrag*)&PT[(16 * wv + r) * STRB + 8 * gq];
        bfrag pa1 = *(const bfrag*)&PT[(16 * wv + r) * STRB + 32 + 8 * gq];
        f32x4 acc2[4] = {bias, bias, bias, bias};
        #pragma unroll
        for (int nt = 0; nt < 4; ++nt) {
            bfrag bh0 = *(const bfrag*)&Ah[(16 * nt + r) * STRB + 8 * gq];
            bfrag bh1 = *(const bfrag*)&Ah[(16 * nt + r) * STRB + 32 + 8 * gq];
            acc2[nt] = __builtin_amdgcn_mfma_f32_16x16x32_bf16(pa0, bh0, acc2[nt], 0, 0, 0);
            acc2[nt] = __builtin_amdgcn_mfma_f32_16x16x32_bf16(pa1, bh1, acc2[nt], 0, 0, 0);
        }

        // ---- stage image i+1 into Xs (safe: pass-A Xs reads completed pre-barrier;
        //      pass B touches only PT/Ah). vmcnt wait here covers ~1 full iteration.
        if (i < 3) {
            #pragma unroll
            for (int q = 0; q < 4; ++q) {
                int idx = tid + q * 256;
                int row = idx >> 4;
                int col = (idx & 15) * 4;
                us4 v;
                v[0] = f2bf(xn[q].x); v[1] = f2bf(xn[q].y);
                v[2] = f2bf(xn[q].z); v[3] = f2bf(xn[q].w);
                *(us4*)&Xs[row * STRB + col] = v;
            }
        }
        // ---- refill prefetch with image i+2 (consumed next iteration)
        if (i < 2) {
            const float4* xg = (const float4*)(x + img0 + (size_t)(i + 2) * imgStride);
            #pragma unroll
            for (int q = 0; q < 4; ++q) xn[q] = xg[tid + q * 256];
        }

        // ---- store Z[i]: lane holds Z[oh=16nt+r][ow=16wv+4gq+j], j contiguous.
        //      Nontemporal: keep out-stream from evicting x in the Infinity Cache.
        {
            float* og = out + img0 + (size_t)i * imgStride;
            #pragma unroll
            for (int nt = 0; nt < 4; ++nt) {
                __builtin_nontemporal_store(
                    acc2[nt],
                    (f32x4*)&og[(size_t)(16 * nt + r) * 64 + 16 * wv + 4 * gq]);
            }
        }

        lds_barrier();   // Xs[i+1] visible; all PT reads done -> PT writable
    }
}

extern "C" void kernel_launch(void* const* d_in, const int* in_sizes, int n_in,
                              void* d_out, int out_size, void* d_ws, size_t ws_size,
                              hipStream_t stream)
{
    const float* x   = (const float*)d_in[0];
    const float* hwt = (const float*)d_in[1];
    const float* wwt = (const float*)d_in[2];
    const float* hb  = (const float*)d_in[3];
    const float* wb  = (const float*)d_in[4];
    oversize_conv_v5<<<1024, 256, 0, stream>>>(x, hwt, wwt, hb, wb, (float*)d_out);
}

// Round 6
// 26.059 us; speedup vs baseline: 1.1679x; 1.1679x over previous
//
#include <hip/hip_runtime.h>

// OversizeConv2d via MFMA: Z = A_h * X * A_w^T + hb*s_w[ow] + wb per (b,c) image.
// Pass A: P = X * Aw^T (X staged coalesced into LDS, bf16).
// Pass B (operand-swapped): Z^T = PT * Ah^T -> j-contiguous float4 stores (NOT nontemporal).
// Toeplitz B-fragments hoisted into registers (loop-invariant): 16 ds_read_b128 -> once.
// Block = one channel, 4 images; grid 1024. Prefetch distance = 1 full iteration.

#define STRB 72   // bf16 LDS row stride: 144 B

typedef short  bfrag  __attribute__((ext_vector_type(8)));   // 8 bf16 = 4 VGPR
typedef float  f32x4  __attribute__((ext_vector_type(4)));
typedef unsigned short us4 __attribute__((ext_vector_type(4)));

__device__ __forceinline__ unsigned short f2bf(float f) {
    unsigned u = __builtin_bit_cast(unsigned, f);
    u += 0x7fffu + ((u >> 16) & 1u);          // round-to-nearest-even
    return (unsigned short)(u >> 16);
}

// LDS-visibility barrier WITHOUT vmcnt drain (keeps global loads/stores in flight)
__device__ __forceinline__ void lds_barrier() {
    asm volatile("s_waitcnt lgkmcnt(0)" ::: "memory");
    __builtin_amdgcn_s_barrier();
}

__global__ __launch_bounds__(256, 4)
void oversize_conv_v6(const float* __restrict__ x,
                      const float* __restrict__ hwt,   // (128,1,13,1)
                      const float* __restrict__ wwt,   // (128,1,1,13)
                      const float* __restrict__ hb,
                      const float* __restrict__ wb,
                      float* __restrict__ out)
{
    __shared__ __align__(16) unsigned short Xs[64 * STRB];  // X bf16 [h][w]
    __shared__ __align__(16) unsigned short Aw[64 * STRB];  // Aw[ow][iw] (build-once)
    __shared__ __align__(16) unsigned short Ah[64 * STRB];  // Ah[oh][ih] (build-once)
    __shared__ __align__(16) unsigned short PT[64 * STRB];  // P^T [ow][h]
    __shared__ float hk[128], wk[128], swp[256];
    __shared__ __align__(16) float sw[64];

    const int tid = threadIdx.x;
    const int c   = blockIdx.x & 127;          // channel
    const int g4  = blockIdx.x >> 7;           // batches 4*g4 .. 4*g4+3
    const size_t imgStride = (size_t)128 * 4096;
    const size_t img0 = ((size_t)(4 * g4) * 128 + c) * 4096;

    const int wv = tid >> 6, lane = tid & 63;
    const int r = lane & 15, gq = lane >> 4;

    // ---- image 0 -> regs, fully coalesced (issue before setup math)
    float4 xv[4];
    {
        const float4* xg = (const float4*)(x + img0);
        #pragma unroll
        for (int q = 0; q < 4; ++q) xv[q] = xg[tid + q * 256];
    }

    // ---- interpolate 13 -> 127 taps (align_corners linear)
    if (tid < 127) {
        const float scale = 12.0f / 126.0f;
        float pos = (float)tid * scale;
        int   lo  = (int)pos;
        float fr  = pos - (float)lo;
        int   hi  = (lo + 1 < 12) ? lo + 1 : 12;
        hk[tid] = hwt[c * 13 + lo] * (1.0f - fr) + hwt[c * 13 + hi] * fr;
        wk[tid] = wwt[c * 13 + lo] * (1.0f - fr) + wwt[c * 13 + hi] * fr;
    }
    lds_barrier();

    // ---- build Toeplitz factors (bf16) + s_w partials, once per block
    {
        const int row = tid >> 2;            // 0..63
        const int cb  = (tid & 3) * 16;
        #pragma unroll
        for (int q = 0; q < 4; ++q) {
            us4 vh, vw;
            #pragma unroll
            for (int j = 0; j < 4; ++j) {
                int col = cb + q * 4 + j;
                vh[j] = f2bf(hk[col - row + 63]);
                vw[j] = f2bf(wk[col - row + 63]);
            }
            *(us4*)&Ah[row * STRB + cb + q * 4] = vh;
            *(us4*)&Aw[row * STRB + cb + q * 4] = vw;
        }
    }
    {
        const int ow = tid >> 2, q = tid & 3;
        float s = 0.f;
        #pragma unroll
        for (int i = 0; i < 16; ++i) s += wk[(q * 16 + i) - ow + 63];
        swp[tid] = s;
    }
    lds_barrier();   // Aw/Ah/swp complete

    // ---- hoist loop-invariant B-fragments into registers (64 VGPR)
    bfrag bA0[4], bA1[4], bH0[4], bH1[4];
    #pragma unroll
    for (int nt = 0; nt < 4; ++nt) {
        bA0[nt] = *(const bfrag*)&Aw[(16 * nt + r) * STRB + 8 * gq];
        bA1[nt] = *(const bfrag*)&Aw[(16 * nt + r) * STRB + 32 + 8 * gq];
        bH0[nt] = *(const bfrag*)&Ah[(16 * nt + r) * STRB + 8 * gq];
        bH1[nt] = *(const bfrag*)&Ah[(16 * nt + r) * STRB + 32 + 8 * gq];
    }
    if (tid < 64)
        sw[tid] = swp[4 * tid] + swp[4 * tid + 1] + swp[4 * tid + 2] + swp[4 * tid + 3];

    // ---- stage image 0 into Xs
    #pragma unroll
    for (int q = 0; q < 4; ++q) {
        int idx = tid + q * 256;
        int row = idx >> 4;
        int col = (idx & 15) * 4;
        us4 v;
        v[0] = f2bf(xv[q].x); v[1] = f2bf(xv[q].y);
        v[2] = f2bf(xv[q].z); v[3] = f2bf(xv[q].w);
        *(us4*)&Xs[row * STRB + col] = v;
    }
    // ---- prefetch image 1 (consumed at bottom of iter 0)
    float4 xn[4];
    {
        const float4* xg = (const float4*)(x + img0 + imgStride);
        #pragma unroll
        for (int q = 0; q < 4; ++q) xn[q] = xg[tid + q * 256];
    }
    lds_barrier();   // Xs + sw visible

    const float hbc = hb[c], wbc = wb[c];
    f32x4 sw4 = *(const f32x4*)&sw[16 * wv + 4 * gq];
    f32x4 bias;
    bias[0] = hbc * sw4[0] + wbc; bias[1] = hbc * sw4[1] + wbc;
    bias[2] = hbc * sw4[2] + wbc; bias[3] = hbc * sw4[3] + wbc;

    #pragma unroll
    for (int i = 0; i < 4; ++i) {
        // ---- pass A: P = X * Aw^T (wave wv owns P rows 16wv..16wv+15)
        bfrag a0 = *(const bfrag*)&Xs[(16 * wv + r) * STRB + 8 * gq];
        bfrag a1 = *(const bfrag*)&Xs[(16 * wv + r) * STRB + 32 + 8 * gq];
        f32x4 acc[4] = {};
        #pragma unroll
        for (int nt = 0; nt < 4; ++nt) {
            acc[nt] = __builtin_amdgcn_mfma_f32_16x16x32_bf16(a0, bA0[nt], acc[nt], 0, 0, 0);
            acc[nt] = __builtin_amdgcn_mfma_f32_16x16x32_bf16(a1, bA1[nt], acc[nt], 0, 0, 0);
        }
        // ---- write P transposed: PT[ow=16nt+r][h=16wv+4gq+j]
        #pragma unroll
        for (int nt = 0; nt < 4; ++nt) {
            us4 p;
            p[0] = f2bf(acc[nt][0]); p[1] = f2bf(acc[nt][1]);
            p[2] = f2bf(acc[nt][2]); p[3] = f2bf(acc[nt][3]);
            *(us4*)&PT[(16 * nt + r) * STRB + 16 * wv + 4 * gq] = p;
        }
        lds_barrier();   // PT visible; all Xs reads done

        // ---- pass B (swapped): Z^T = PT * Ah^T
        bfrag pa0 = *(const bfrag*)&PT[(16 * wv + r) * STRB + 8 * gq];
        bfrag pa1 = *(const bfrag*)&PT[(16 * wv + r) * STRB + 32 + 8 * gq];
        f32x4 acc2[4] = {bias, bias, bias, bias};
        #pragma unroll
        for (int nt = 0; nt < 4; ++nt) {
            acc2[nt] = __builtin_amdgcn_mfma_f32_16x16x32_bf16(pa0, bH0[nt], acc2[nt], 0, 0, 0);
            acc2[nt] = __builtin_amdgcn_mfma_f32_16x16x32_bf16(pa1, bH1[nt], acc2[nt], 0, 0, 0);
        }

        // ---- stage image i+1 into Xs (Xs reads finished before mid barrier)
        if (i < 3) {
            #pragma unroll
            for (int q = 0; q < 4; ++q) {
                int idx = tid + q * 256;
                int row = idx >> 4;
                int col = (idx & 15) * 4;
                us4 v;
                v[0] = f2bf(xn[q].x); v[1] = f2bf(xn[q].y);
                v[2] = f2bf(xn[q].z); v[3] = f2bf(xn[q].w);
                *(us4*)&Xs[row * STRB + col] = v;
            }
        }
        // ---- refill prefetch with image i+2 (consumed next iteration)
        if (i < 2) {
            const float4* xg = (const float4*)(x + img0 + (size_t)(i + 2) * imgStride);
            #pragma unroll
            for (int q = 0; q < 4; ++q) xn[q] = xg[tid + q * 256];
        }

        // ---- store Z[i]: lane holds Z[oh=16nt+r][ow=16wv+4gq+j], plain f32x4
        {
            float* og = out + img0 + (size_t)i * imgStride;
            #pragma unroll
            for (int nt = 0; nt < 4; ++nt) {
                f32x4 v = acc2[nt];
                *(f32x4*)&og[(size_t)(16 * nt + r) * 64 + 16 * wv + 4 * gq] = v;
            }
        }

        lds_barrier();   // Xs[i+1] visible; all PT reads done
    }
}

extern "C" void kernel_launch(void* const* d_in, const int* in_sizes, int n_in,
                              void* d_out, int out_size, void* d_ws, size_t ws_size,
                              hipStream_t stream)
{
    const float* x   = (const float*)d_in[0];
    const float* hwt = (const float*)d_in[1];
    const float* wwt = (const float*)d_in[2];
    const float* hb  = (const float*)d_in[3];
    const float* wb  = (const float*)d_in[4];
    oversize_conv_v6<<<1024, 256, 0, stream>>>(x, hwt, wwt, hb, wb, (float*)d_out);
}